// Round 2
// baseline (256.729 us; speedup 1.0000x reference)
//
#include <hip/hip_runtime.h>

typedef short short8 __attribute__((ext_vector_type(8)));
typedef float f32x4 __attribute__((ext_vector_type(4)));
typedef unsigned short US;

// ---------- helpers ----------
__device__ __forceinline__ float bf2f(US u) {
    return __uint_as_float(((unsigned int)u) << 16);
}
__device__ __forceinline__ US f2bf(float f) {
    unsigned int x = __float_as_uint(f);
    return (US)((x + 0x7FFFu + ((x >> 16) & 1u)) >> 16);
}
__device__ __forceinline__ float tanh_fast(float x) {
    // tanh(x) = 1 - 2/(exp(2x)+1); exp->inf/0 limits give +-1 correctly
    float e = __expf(2.0f * x);
    return 1.0f - __fdividef(2.0f, e + 1.0f);
}
// split fp32 -> bf16 hi + bf16 lo (a ~= hi + lo, rel err ~2^-17)
__device__ __forceinline__ void split8(const float* p, short8& hi, short8& lo) {
    float4 a = *(const float4*)p;
    float4 c = *(const float4*)(p + 4);
    float f[8] = {a.x, a.y, a.z, a.w, c.x, c.y, c.z, c.w};
    #pragma unroll
    for (int j = 0; j < 8; ++j) {
        US h = f2bf(f[j]);
        float rh = bf2f(h);
        US l = f2bf(f[j] - rh);
        hi[j] = (short)h;
        lo[j] = (short)l;
    }
}

// B=4, N=M=256, D=256, H=128 (hard-coded for this problem)

// ---------- kernel 1: cast x0,x1 -> bf16 ----------
__global__ void cast_bf16_kernel(const float* __restrict__ x0, const float* __restrict__ x1,
                                 US* __restrict__ x0b, US* __restrict__ x1b) {
    int tid = blockIdx.x * 256 + threadIdx.x;  // 0..131071, 65536 float4 per tensor
    const float* src;
    US* dst;
    int idx;
    if (tid < 65536) { src = x0; dst = x0b; idx = tid; }
    else             { src = x1; dst = x1b; idx = tid - 65536; }
    float4 v = ((const float4*)src)[idx];
    ushort4 o;
    o.x = f2bf(v.x); o.y = f2bf(v.y); o.z = f2bf(v.z); o.w = f2bf(v.w);
    ((ushort4*)dst)[idx] = o;
}

// ---------- kernel 2: Wd1,Wd2 [D=256][H=128] f32 -> WdT [H][D] bf16 ----------
__global__ void transpose_wd_kernel(const float* __restrict__ Wd1, const float* __restrict__ Wd2,
                                    US* __restrict__ WdT1, US* __restrict__ WdT2) {
    int bl = blockIdx.x;  // 0..255
    const float* src = (bl < 128) ? Wd1 : Wd2;
    US* dst = (bl < 128) ? WdT1 : WdT2;
    int r2 = bl & 127;
    int t = threadIdx.x;
    int d = r2 * 2 + (t >> 7);
    int h = t & 127;
    dst[h * 256 + d] = f2bf(src[d * 128 + h]);
}

// ---------- kernel 3: small GEMMs (VALU) ----------
// which==0 (x0 rows): S1T[b][h][n] = (x0@Wc1)^T ; SXT[b][h][n] = (x0@Wm)^T ; XBf[b][n][:] = x0@Wb (fp32)
// which==1 (x1 rows): S2[b][m][h] = x1@Wc2 ; SY[b][m][h] = x1@Wm
__global__ void small_gemms_kernel(const float* __restrict__ x0, const float* __restrict__ x1,
                                   const float* __restrict__ Wc1, const float* __restrict__ Wc2,
                                   const float* __restrict__ Wm, const float* __restrict__ Wb,
                                   float* __restrict__ S1T, float* __restrict__ SXT,
                                   float* __restrict__ S2, float* __restrict__ SY,
                                   float* __restrict__ XBf) {
    __shared__ float xl[256];
    int id = blockIdx.x;
    int which = id >> 10;
    int rem = id & 1023;
    int b = rem >> 8, row = rem & 255;
    int t = threadIdx.x;
    const float* x = (which == 0 ? x0 : x1) + (size_t)(b * 256 + row) * 256;
    xl[t] = x[t];
    __syncthreads();
    int cA = t & 127;
    if (which == 0) {
        const float* WA = (t < 128) ? Wc1 : Wm;
        float accA = 0.f, accB = 0.f;
        #pragma unroll 4
        for (int d = 0; d < 256; ++d) {
            float xv = xl[d];
            accA = fmaf(xv, WA[d * 128 + cA], accA);
            accB = fmaf(xv, Wb[d * 256 + t], accB);
        }
        if (t < 128) S1T[(size_t)(b * 128 + cA) * 256 + row] = accA;
        else         SXT[(size_t)(b * 128 + cA) * 256 + row] = accA;
        XBf[(size_t)(b * 256 + row) * 256 + t] = accB;
    } else {
        const float* WA = (t < 128) ? Wc2 : Wm;
        float accA = 0.f;
        #pragma unroll 4
        for (int d = 0; d < 256; ++d)
            accA = fmaf(xl[d], WA[d * 128 + cA], accA);
        if (t < 128) S2[(size_t)(b * 256 + row) * 128 + cA] = accA;
        else         SY[(size_t)(b * 256 + row) * 128 + cA] = accA;
    }
}

// ---------- kernel 4: dot-att scores via MFMA ----------
// mech 0: sjt_s[b][m][n] = sum_h tanh( sum_d x0[b,n,d]*x1[b,m,d]*Wd1[d,h] ) * vd1[h]
// mech 1: sjt_d[b][m][n] = same with x1<->x0, Wd2, vd2
__global__ __launch_bounds__(256, 2)
void dot_scores_kernel(const US* __restrict__ x0b, const US* __restrict__ x1b,
                       const float* __restrict__ x0, const float* __restrict__ x1,
                       const US* __restrict__ WdT1, const US* __restrict__ WdT2,
                       const float* __restrict__ vd1, const float* __restrict__ vd2,
                       float* __restrict__ sjt_s, float* __restrict__ sjt_d) {
    __shared__ __align__(16) US Wp[128 * 256];  // W'^T [H][D] bf16, 16B-block XOR swizzled
    const int id = blockIdx.x;
    const int mech = id >> 10;
    const int rem = id & 1023;
    const int b = rem >> 8;
    const int m = rem & 255;
    const US* xA = (mech == 0 ? x0b : x1b) + (size_t)b * 65536;
    const float* yrow = (mech == 0 ? x1 : x0) + (size_t)(b * 256 + m) * 256;
    const US* WT = (mech == 0 ? WdT1 : WdT2);
    const float* v = (mech == 0 ? vd1 : vd2);
    float* out = (mech == 0 ? sjt_s : sjt_d) + (size_t)(b * 256 + m) * 256;

    const int t = threadIdx.x;
    // ---- stage W'^T[h][d] = y[d] * WdT[h][d] into LDS (swizzled) ----
    {
        const int h = t >> 1;
        const int half = t & 1;
        const US* wrow = WT + h * 256;
        #pragma unroll
        for (int c = 0; c < 16; ++c) {
            const int bd = half * 16 + c;  // 16B block index along d
            const int d = bd * 8;
            short8 wv = *(const short8*)(wrow + d);
            float4 y0 = *(const float4*)(yrow + d);
            float4 y1 = *(const float4*)(yrow + d + 4);
            float yv[8] = {y0.x, y0.y, y0.z, y0.w, y1.x, y1.y, y1.z, y1.w};
            short8 ov;
            #pragma unroll
            for (int j = 0; j < 8; ++j)
                ov[j] = (short)f2bf(bf2f((US)wv[j]) * yv[j]);
            const int sb = bd ^ (h & 7);
            *(short8*)(&Wp[h * 256 + sb * 8]) = ov;
        }
    }
    __syncthreads();

    const int lane = t & 63;
    const int w = t >> 6;        // wave: n-range [64w, 64w+64)
    const int arow = lane & 15;  // A row / D col
    const int kgrp = lane >> 4;  // k-group

    float vv[8];
    #pragma unroll
    for (int ht = 0; ht < 8; ++ht) vv[ht] = v[ht * 16 + arow];

    float pacc[4][4];
    #pragma unroll
    for (int i = 0; i < 4; ++i)
        #pragma unroll
        for (int r = 0; r < 4; ++r) pacc[i][r] = 0.0f;

    const f32x4 vzero = {0.0f, 0.0f, 0.0f, 0.0f};

    #pragma unroll
    for (int hp = 0; hp < 2; ++hp) {  // h-half pass: h-tiles hp*4 .. hp*4+3
        f32x4 acc[4][4];
        #pragma unroll
        for (int i = 0; i < 4; ++i)
            #pragma unroll
            for (int j = 0; j < 4; ++j) acc[i][j] = vzero;

        for (int kk = 0; kk < 8; ++kk) {
            short8 bfrag[4];
            #pragma unroll
            for (int j = 0; j < 4; ++j) {
                const int h = (hp * 4 + j) * 16 + arow;
                const int bd = kk * 4 + kgrp;
                const int sb = bd ^ (h & 7);
                bfrag[j] = *(const short8*)(&Wp[h * 256 + sb * 8]);
            }
            short8 afrag[4];
            #pragma unroll
            for (int i = 0; i < 4; ++i) {
                const int n = w * 64 + i * 16 + arow;
                afrag[i] = *(const short8*)(xA + (size_t)n * 256 + kk * 32 + kgrp * 8);
            }
            #pragma unroll
            for (int i = 0; i < 4; ++i)
                #pragma unroll
                for (int j = 0; j < 4; ++j)
                    acc[i][j] = __builtin_amdgcn_mfma_f32_16x16x32_bf16(afrag[i], bfrag[j], acc[i][j], 0, 0, 0);
        }
        // fold tanh * v into per-lane partials (lane holds h = (hp*4+j)*16+arow, n = 64w+16i+4*kgrp+r)
        #pragma unroll
        for (int i = 0; i < 4; ++i)
            #pragma unroll
            for (int r = 0; r < 4; ++r) {
                float p = 0.0f;
                #pragma unroll
                for (int j = 0; j < 4; ++j)
                    p = fmaf(tanh_fast(acc[i][j][r]), vv[hp * 4 + j], p);
                pacc[i][r] += p;
            }
    }

    // reduce over the 16 h-lanes (bits 0..3 of lane) and write sjt
    #pragma unroll
    for (int i = 0; i < 4; ++i)
        #pragma unroll
        for (int r = 0; r < 4; ++r) {
            float p = pacc[i][r];
            p += __shfl_xor(p, 1);
            p += __shfl_xor(p, 2);
            p += __shfl_xor(p, 4);
            p += __shfl_xor(p, 8);
            if (arow == 0) out[w * 64 + i * 16 + kgrp * 4 + r] = p;
        }
}

// ---------- kernel 5: bilinear scores via split-bf16 MFMA (fp32-equivalent) ----------
// sjt_b[b][m][n] = sum_d x1[b,m,d] * XB[b,n,d]   (logits have std ~16 -> need fp32 precision)
__global__ __launch_bounds__(256)
void bilinear_kernel(const float* __restrict__ x1, const float* __restrict__ XBf,
                     float* __restrict__ sjt_b) {
    const int id = blockIdx.x;  // 16 blocks
    const int b = id >> 2;
    const int mt = id & 3;
    const int t = threadIdx.x;
    const int lane = t & 63;
    const int w = t >> 6;
    const int arow = lane & 15;
    const int kgrp = lane >> 4;
    const float* A = x1 + (size_t)b * 65536;
    const float* Bt = XBf + (size_t)b * 65536;
    const int m0 = mt * 64 + w * 16;
    const f32x4 vzero = {0.0f, 0.0f, 0.0f, 0.0f};
    f32x4 acc[16];
    #pragma unroll
    for (int nt = 0; nt < 16; ++nt) acc[nt] = vzero;
    for (int kk = 0; kk < 8; ++kk) {
        short8 ahi, alo;
        split8(A + (size_t)(m0 + arow) * 256 + kk * 32 + kgrp * 8, ahi, alo);
        #pragma unroll
        for (int nt = 0; nt < 16; ++nt) {
            short8 bhi, blo;
            split8(Bt + (size_t)(nt * 16 + arow) * 256 + kk * 32 + kgrp * 8, bhi, blo);
            acc[nt] = __builtin_amdgcn_mfma_f32_16x16x32_bf16(alo, bhi, acc[nt], 0, 0, 0);
            acc[nt] = __builtin_amdgcn_mfma_f32_16x16x32_bf16(ahi, blo, acc[nt], 0, 0, 0);
            acc[nt] = __builtin_amdgcn_mfma_f32_16x16x32_bf16(ahi, bhi, acc[nt], 0, 0, 0);
        }
    }
    float* outb = sjt_b + (size_t)b * 65536;
    #pragma unroll
    for (int nt = 0; nt < 16; ++nt) {
        #pragma unroll
        for (int r = 0; r < 4; ++r) {
            const int mm = m0 + kgrp * 4 + r;
            const int nn = nt * 16 + arow;
            outb[(size_t)mm * 256 + nn] = acc[nt][r];
        }
    }
}

// ---------- kernel 6: concat + minus scores (VALU tanh) ----------
__global__ void concat_minus_kernel(const float* __restrict__ S1T, const float* __restrict__ SXT,
                                    const float* __restrict__ S2, const float* __restrict__ SY,
                                    const float* __restrict__ vc, const float* __restrict__ vm,
                                    float* __restrict__ sjt_c, float* __restrict__ sjt_m) {
    __shared__ float s2l[128], syl[128], vcl[128], vml[128];
    int id = blockIdx.x;
    int b = id >> 8, m = id & 255;
    int t = threadIdx.x;
    if (t < 128) {
        s2l[t] = S2[(size_t)(b * 256 + m) * 128 + t];
        vcl[t] = vc[t];
    } else {
        int h = t - 128;
        syl[h] = SY[(size_t)(b * 256 + m) * 128 + h];
        vml[h] = vm[h];
    }
    __syncthreads();
    const float* s1p = S1T + (size_t)b * 128 * 256 + t;
    const float* sxp = SXT + (size_t)b * 128 * 256 + t;
    float accC = 0.f, accM = 0.f;
    #pragma unroll 4
    for (int h = 0; h < 128; ++h) {
        float s1 = s1p[h * 256];
        float sx = sxp[h * 256];
        accC = fmaf(tanh_fast(s1 + s2l[h]), vcl[h], accC);
        accM = fmaf(tanh_fast(sx - syl[h]), vml[h], accM);
    }
    sjt_c[(size_t)(b * 256 + m) * 256 + t] = accC;
    sjt_m[(size_t)(b * 256 + m) * 256 + t] = accM;
}

// ---------- kernel 7: softmax x5 + weighted sums + max ----------
__global__ void finalize_kernel(const float* __restrict__ sjt_c, const float* __restrict__ sjt_m,
                                const float* __restrict__ sjt_b, const float* __restrict__ sjt_s,
                                const float* __restrict__ sjt_d,
                                const US* __restrict__ x0b, const US* __restrict__ x1b,
                                const float* __restrict__ x1, float* __restrict__ outp) {
    __shared__ float srow[5][256];
    int id = blockIdx.x;
    int b = id >> 8, m = id & 255;
    int t = threadIdx.x;
    size_t bm = (size_t)(b * 256 + m) * 256;
    srow[0][t] = sjt_c[bm + t];
    srow[1][t] = sjt_m[bm + t];
    srow[2][t] = sjt_b[bm + t];
    srow[3][t] = sjt_s[bm + t];
    srow[4][t] = sjt_d[bm + t];
    __syncthreads();
    int wv = t >> 6, lane = t & 63;
    for (int r = wv; r < 5; r += 4) {
        float v0 = srow[r][lane], v1 = srow[r][lane + 64];
        float v2 = srow[r][lane + 128], v3 = srow[r][lane + 192];
        float mx = fmaxf(fmaxf(v0, v1), fmaxf(v2, v3));
        #pragma unroll
        for (int off = 32; off >= 1; off >>= 1) mx = fmaxf(mx, __shfl_xor(mx, off));
        v0 = __expf(v0 - mx); v1 = __expf(v1 - mx);
        v2 = __expf(v2 - mx); v3 = __expf(v3 - mx);
        float s = v0 + v1 + v2 + v3;
        #pragma unroll
        for (int off = 32; off >= 1; off >>= 1) s += __shfl_xor(s, off);
        float inv = __fdividef(1.0f, s);
        srow[r][lane] = v0 * inv;       srow[r][lane + 64] = v1 * inv;
        srow[r][lane + 128] = v2 * inv; srow[r][lane + 192] = v3 * inv;
    }
    __syncthreads();
    const US* x0p = x0b + (size_t)b * 65536 + t;
    const US* x1p = x1b + (size_t)b * 65536 + t;
    float aC = 0.f, aM = 0.f, aB = 0.f, aS = 0.f, aD = 0.f;
    #pragma unroll 4
    for (int n = 0; n < 256; ++n) {
        float x0v = bf2f(x0p[n * 256]);
        float x1v = bf2f(x1p[n * 256]);
        aC = fmaf(srow[0][n], x0v, aC);
        aM = fmaf(srow[1][n], x0v, aM);
        aB = fmaf(srow[2][n], x0v, aB);
        aS = fmaf(srow[3][n], x0v, aS);
        aD = fmaf(srow[4][n], x1v, aD);
    }
    float x1orig = x1[bm + t];
    float o = fmaxf(fmaxf(fmaxf(x1orig, aS), fmaxf(aC, aD)), fmaxf(aB, aM));
    outp[bm + t] = o;
}

// ---------- host ----------
extern "C" void kernel_launch(void* const* d_in, const int* in_sizes, int n_in,
                              void* d_out, int out_size, void* d_ws, size_t ws_size,
                              hipStream_t stream) {
    (void)in_sizes; (void)n_in; (void)out_size; (void)ws_size;
    const float* x0  = (const float*)d_in[0];
    const float* x1  = (const float*)d_in[1];
    const float* Wc1 = (const float*)d_in[2];
    const float* Wc2 = (const float*)d_in[3];
    const float* vc  = (const float*)d_in[4];
    const float* Wb  = (const float*)d_in[5];
    const float* Wd1 = (const float*)d_in[6];
    const float* vd1 = (const float*)d_in[7];
    const float* Wd2 = (const float*)d_in[8];
    const float* vd2 = (const float*)d_in[9];
    const float* Wm  = (const float*)d_in[10];
    const float* vm  = (const float*)d_in[11];

    char* ws = (char*)d_ws;
    US*    x0b   = (US*)(ws + 0);          // 524288
    US*    x1b   = (US*)(ws + 524288);     // 524288
    US*    WdT1  = (US*)(ws + 1048576);    // 65536
    US*    WdT2  = (US*)(ws + 1114112);    // 65536
    float* S1T   = (float*)(ws + 1179648); // 524288
    float* SXT   = (float*)(ws + 1703936); // 524288
    float* S2    = (float*)(ws + 2228224); // 524288
    float* SY    = (float*)(ws + 2752512); // 524288
    float* XBf   = (float*)(ws + 3276800); // 1048576 (fp32 now)
    float* sjt_c = (float*)(ws + 4325376); // 1048576
    float* sjt_m = (float*)(ws + 5373952);
    float* sjt_b = (float*)(ws + 6422528);
    float* sjt_s = (float*)(ws + 7471104);
    float* sjt_d = (float*)(ws + 8519680); // ends at 9568256

    cast_bf16_kernel<<<512, 256, 0, stream>>>(x0, x1, x0b, x1b);
    transpose_wd_kernel<<<256, 256, 0, stream>>>(Wd1, Wd2, WdT1, WdT2);
    small_gemms_kernel<<<2048, 256, 0, stream>>>(x0, x1, Wc1, Wc2, Wm, Wb, S1T, SXT, S2, SY, XBf);
    dot_scores_kernel<<<2048, 256, 0, stream>>>(x0b, x1b, x0, x1, WdT1, WdT2, vd1, vd2, sjt_s, sjt_d);
    bilinear_kernel<<<16, 256, 0, stream>>>(x1, XBf, sjt_b);
    concat_minus_kernel<<<1024, 256, 0, stream>>>(S1T, SXT, S2, SY, vc, vm, sjt_c, sjt_m);
    finalize_kernel<<<1024, 256, 0, stream>>>(sjt_c, sjt_m, sjt_b, sjt_s, sjt_d, x0b, x1b, x1, (float*)d_out);
}

// Round 3
// 193.524 us; speedup vs baseline: 1.3266x; 1.3266x over previous
//
#include <hip/hip_runtime.h>
#include <math.h>

typedef short short8 __attribute__((ext_vector_type(8)));
typedef float f32x4 __attribute__((ext_vector_type(4)));
typedef unsigned short US;

#if __has_builtin(__builtin_amdgcn_exp2f)
#define EXP2(x) __builtin_amdgcn_exp2f(x)
#else
#define EXP2(x) exp2f(x)
#endif
#define RCP(x) __builtin_amdgcn_rcpf(x)

#define C2 2.8853900817779268f  /* 2*log2(e) */

// ---------- helpers ----------
__device__ __forceinline__ float bf2f(US u) {
    return __uint_as_float(((unsigned int)u) << 16);
}
// exact RNE float->bf16
__device__ __forceinline__ US f2bf(float f) {
    unsigned int x = __float_as_uint(f);
    return (US)((x + 0x7FFFu + ((x >> 16) & 1u)) >> 16);
}
// round-half-up float->bf16 (cheap, <=0.5ulp)
__device__ __forceinline__ US f2bf_fast(float f) {
    return (US)((__float_as_uint(f) + 0x8000u) >> 16);
}

// B=4, N=M=256, D=256, H=128 (hard-coded)

// ---------- kernel 1: prep (casts + transposes) ----------
// id<512: x0/x1 -> hi+lo bf16. [512,1152): 5x W[256][128]->WT[128][256] bf16.
// [1152,1408): Wb[256][256] -> WbT hi/lo [256][256] bf16.
__global__ void prep_kernel(const float* __restrict__ x0, const float* __restrict__ x1,
                            const float* __restrict__ Wc1, const float* __restrict__ Wc2,
                            const float* __restrict__ Wm, const float* __restrict__ Wd1,
                            const float* __restrict__ Wd2, const float* __restrict__ Wb,
                            US* __restrict__ x0b, US* __restrict__ x1b,
                            US* __restrict__ x0lo, US* __restrict__ x1lo,
                            US* __restrict__ WcT1, US* __restrict__ WcT2,
                            US* __restrict__ WmT, US* __restrict__ WdT1, US* __restrict__ WdT2,
                            US* __restrict__ WbThi, US* __restrict__ WbTlo) {
    const int id = blockIdx.x;
    const int t = threadIdx.x;
    if (id < 512) {
        const int tensor = id >> 8;
        const float* src = tensor ? x1 : x0;
        US* dhi = tensor ? x1b : x0b;
        US* dlo = tensor ? x1lo : x0lo;
        const int idx = (id & 255) * 256 + t;  // float4 index
        float4 v = ((const float4*)src)[idx];
        float f[4] = {v.x, v.y, v.z, v.w};
        ushort4 hi, lo;
        US* hp = (US*)&hi;
        US* lp = (US*)&lo;
        #pragma unroll
        for (int j = 0; j < 4; ++j) {
            US h = f2bf(f[j]);
            hp[j] = h;
            lp[j] = f2bf(f[j] - bf2f(h));
        }
        ((ushort4*)dhi)[idx] = hi;
        ((ushort4*)dlo)[idx] = lo;
    } else if (id < 1152) {
        const int j = id - 512;
        const int mat = j >> 7;
        const float* src = (mat == 0) ? Wc1 : (mat == 1) ? Wc2 : (mat == 2) ? Wm : (mat == 3) ? Wd1 : Wd2;
        US* dst = (mat == 0) ? WcT1 : (mat == 1) ? WcT2 : (mat == 2) ? WmT : (mat == 3) ? WdT1 : WdT2;
        const int el = (j & 127) * 256 + t;
        const int d = el >> 7, h = el & 127;
        dst[h * 256 + d] = f2bf(src[d * 128 + h]);
    } else {
        const int j = id - 1152;
        const int el = j * 256 + t;
        const int d = el >> 8, dp = el & 255;
        float v = Wb[d * 256 + dp];
        US h = f2bf(v);
        WbThi[dp * 256 + d] = h;
        WbTlo[dp * 256 + d] = f2bf(v - bf2f(h));
    }
}

// ---------- kernel 2: fused small GEMMs via MFMA ----------
// which0: S1T[b][h][n]=(x0@Wc1)^T, SXT[b][h][n]=(x0@Wm)^T   (bf16 MFMA)
// which1: XB = x0@Wb (hi/lo split, 3 MFMA) -> XBhi/XBlo [b][n][d'] bf16
// which2: S2[b][m][h]=x1@Wc2, SY[b][m][h]=x1@Wm
__global__ __launch_bounds__(256)
void fused_gemms_kernel(const US* __restrict__ x0b, const US* __restrict__ x0lo,
                        const US* __restrict__ x1b,
                        const US* __restrict__ WcT1, const US* __restrict__ WcT2,
                        const US* __restrict__ WmT,
                        const US* __restrict__ WbThi, const US* __restrict__ WbTlo,
                        float* __restrict__ S1T, float* __restrict__ SXT,
                        float* __restrict__ S2, float* __restrict__ SY,
                        US* __restrict__ XBhi, US* __restrict__ XBlo) {
    const int id = blockIdx.x;            // 192 = 4b x 3which x 16rg
    const int rg = id & 15;
    const int t2 = id >> 4;               // 0..11
    const int b = t2 / 3;
    const int which = t2 - b * 3;
    const int t = threadIdx.x;
    const int lane = t & 63;
    const int w = t >> 6;
    const int arow = lane & 15;
    const int kgrp = lane >> 4;

    const US* A = (which == 2 ? x1b : x0b) + (size_t)(b * 256 + rg * 16 + arow) * 256 + kgrp * 8;
    const US* Alo = x0lo + (size_t)(b * 256 + rg * 16 + arow) * 256 + kgrp * 8;

    const f32x4 vzero = {0.f, 0.f, 0.f, 0.f};
    f32x4 acc[4];
    #pragma unroll
    for (int cj = 0; cj < 4; ++cj) acc[cj] = vzero;

    if (which == 1) {
        #pragma unroll
        for (int kk = 0; kk < 8; ++kk) {
            short8 ahi = *(const short8*)(A + kk * 32);
            short8 alo = *(const short8*)(Alo + kk * 32);
            #pragma unroll
            for (int cj = 0; cj < 4; ++cj) {
                const int ct = w * 4 + cj;
                const US* brow = WbThi + (ct * 16 + arow) * 256 + kk * 32 + kgrp * 8;
                const US* browl = WbTlo + (ct * 16 + arow) * 256 + kk * 32 + kgrp * 8;
                short8 bhi = *(const short8*)brow;
                short8 blo = *(const short8*)browl;
                acc[cj] = __builtin_amdgcn_mfma_f32_16x16x32_bf16(ahi, bhi, acc[cj], 0, 0, 0);
                acc[cj] = __builtin_amdgcn_mfma_f32_16x16x32_bf16(ahi, blo, acc[cj], 0, 0, 0);
                acc[cj] = __builtin_amdgcn_mfma_f32_16x16x32_bf16(alo, bhi, acc[cj], 0, 0, 0);
            }
        }
        #pragma unroll
        for (int cj = 0; cj < 4; ++cj) {
            const int ct = w * 4 + cj;
            #pragma unroll
            for (int r = 0; r < 4; ++r) {
                const int n = rg * 16 + kgrp * 4 + r;
                const int dp = ct * 16 + arow;
                float val = acc[cj][r];
                US h = f2bf(val);
                XBhi[(size_t)(b * 256 + n) * 256 + dp] = h;
                XBlo[(size_t)(b * 256 + n) * 256 + dp] = f2bf(val - bf2f(h));
            }
        }
    } else {
        const US* WA = (which == 0) ? WcT1 : WcT2;
        #pragma unroll
        for (int kk = 0; kk < 8; ++kk) {
            short8 a = *(const short8*)(A + kk * 32);
            #pragma unroll
            for (int cj = 0; cj < 4; ++cj) {
                const int ct = w * 4 + cj;
                const US* brow = (ct < 8) ? (WA + (ct * 16 + arow) * 256)
                                          : (WmT + ((ct - 8) * 16 + arow) * 256);
                short8 bf = *(const short8*)(brow + kk * 32 + kgrp * 8);
                acc[cj] = __builtin_amdgcn_mfma_f32_16x16x32_bf16(a, bf, acc[cj], 0, 0, 0);
            }
        }
        #pragma unroll
        for (int cj = 0; cj < 4; ++cj) {
            const int ct = w * 4 + cj;
            #pragma unroll
            for (int r = 0; r < 4; ++r) {
                const int row = rg * 16 + kgrp * 4 + r;
                float val = acc[cj][r];
                if (which == 0) {
                    const int h = (ct < 8) ? ct * 16 + arow : (ct - 8) * 16 + arow;
                    float* dst = (ct < 8) ? S1T : SXT;
                    dst[(size_t)(b * 128 + h) * 256 + row] = val;
                } else {
                    const int h = (ct < 8) ? ct * 16 + arow : (ct - 8) * 16 + arow;
                    float* dst = (ct < 8) ? S2 : SY;
                    dst[(size_t)(b * 256 + row) * 128 + h] = val;
                }
            }
        }
    }
}

// ---------- kernel 3: dot-att scores via MFMA (h-half LDS passes) ----------
__global__ __launch_bounds__(256, 4)
void dot_scores_kernel(const US* __restrict__ x0b, const US* __restrict__ x1b,
                       const float* __restrict__ x0, const float* __restrict__ x1,
                       const US* __restrict__ WdT1, const US* __restrict__ WdT2,
                       const float* __restrict__ vd1, const float* __restrict__ vd2,
                       float* __restrict__ sjt_s, float* __restrict__ sjt_d) {
    __shared__ __align__(16) US Wp[64 * 256];  // 32 KB: h-half of W', 16B-block XOR swizzled
    const int id = blockIdx.x;
    const int mech = id >> 10;
    const int rem = id & 1023;
    const int b = rem >> 8;
    const int m = rem & 255;
    const US* xA = (mech == 0 ? x0b : x1b) + (size_t)b * 65536;
    const float* yrow = (mech == 0 ? x1 : x0) + (size_t)(b * 256 + m) * 256;
    const US* WT = (mech == 0 ? WdT1 : WdT2);
    const float* v = (mech == 0 ? vd1 : vd2);
    float* out = (mech == 0 ? sjt_s : sjt_d) + (size_t)(b * 256 + m) * 256;

    const int t = threadIdx.x;
    const int lane = t & 63;
    const int w = t >> 6;        // wave: n-range [64w, 64w+64)
    const int arow = lane & 15;
    const int kgrp = lane >> 4;

    // staging role: thread covers d-block db (8 d's) x 8 h-rows
    const int db = t & 31;
    const int hset = t >> 5;  // 0..7
    // y values for this thread's d-slice, loaded once
    float yv[8];
    {
        float4 y0 = *(const float4*)(yrow + db * 8);
        float4 y1 = *(const float4*)(yrow + db * 8 + 4);
        yv[0] = y0.x; yv[1] = y0.y; yv[2] = y0.z; yv[3] = y0.w;
        yv[4] = y1.x; yv[5] = y1.y; yv[6] = y1.z; yv[7] = y1.w;
    }

    // v-vector per lane: h = ht*16 + arow
    float v2[8], vsum = 0.f;
    #pragma unroll
    for (int ht = 0; ht < 8; ++ht) {
        float vv = v[ht * 16 + arow];
        v2[ht] = -2.0f * vv;
        vsum += vv;
    }

    float pacc[4][4];
    #pragma unroll
    for (int i = 0; i < 4; ++i)
        #pragma unroll
        for (int r = 0; r < 4; ++r) pacc[i][r] = vsum;

    const f32x4 vzero = {0.f, 0.f, 0.f, 0.f};

    #pragma unroll
    for (int hp = 0; hp < 2; ++hp) {
        __syncthreads();  // protect Wp from previous pass readers
        // ---- stage h-half: W'[h'][d] = y[d]*WdT[hp*64+h'][d] ----
        #pragma unroll
        for (int k = 0; k < 8; ++k) {
            const int hq = hset * 8 + k;
            short8 wv = *(const short8*)(WT + (size_t)(hp * 64 + hq) * 256 + db * 8);
            short8 ov;
            #pragma unroll
            for (int j = 0; j < 8; ++j)
                ov[j] = (short)f2bf_fast(bf2f((US)wv[j]) * yv[j]);
            *(short8*)(&Wp[hq * 256 + ((db ^ (hq & 7)) << 3)]) = ov;
        }
        __syncthreads();

        f32x4 acc[4][4];
        #pragma unroll
        for (int i = 0; i < 4; ++i)
            #pragma unroll
            for (int j = 0; j < 4; ++j) acc[i][j] = vzero;

        #pragma unroll
        for (int kk = 0; kk < 8; ++kk) {
            short8 bfrag[4];
            #pragma unroll
            for (int j = 0; j < 4; ++j) {
                const int hq = j * 16 + arow;
                const int sb = (kk * 4 + kgrp) ^ (arow & 7);
                bfrag[j] = *(const short8*)(&Wp[hq * 256 + sb * 8]);
            }
            short8 afrag[4];
            #pragma unroll
            for (int i = 0; i < 4; ++i) {
                const int n = w * 64 + i * 16 + arow;
                afrag[i] = *(const short8*)(xA + (size_t)n * 256 + kk * 32 + kgrp * 8);
            }
            #pragma unroll
            for (int i = 0; i < 4; ++i)
                #pragma unroll
                for (int j = 0; j < 4; ++j)
                    acc[i][j] = __builtin_amdgcn_mfma_f32_16x16x32_bf16(afrag[i], bfrag[j], acc[i][j], 0, 0, 0);
        }
        // fold: v*tanh(s) = v + v2*rcp(exp2(s*C2)+1)
        #pragma unroll
        for (int i = 0; i < 4; ++i)
            #pragma unroll
            for (int r = 0; r < 4; ++r) {
                float p = pacc[i][r];
                #pragma unroll
                for (int j = 0; j < 4; ++j) {
                    float e = EXP2(acc[i][j][r] * C2);
                    p = fmaf(v2[hp * 4 + j], RCP(e + 1.0f), p);
                }
                pacc[i][r] = p;
            }
    }

    // reduce over the 16 h-lanes and write
    #pragma unroll
    for (int i = 0; i < 4; ++i)
        #pragma unroll
        for (int r = 0; r < 4; ++r) {
            float p = pacc[i][r];
            p += __shfl_xor(p, 1);
            p += __shfl_xor(p, 2);
            p += __shfl_xor(p, 4);
            p += __shfl_xor(p, 8);
            if (arow == 0) out[w * 64 + i * 16 + kgrp * 4 + r] = p;
        }
}

// ---------- kernel 4: bilinear scores (precomputed hi/lo, 3-MFMA) ----------
__global__ __launch_bounds__(256)
void bilinear_kernel(const US* __restrict__ x1b, const US* __restrict__ x1lo,
                     const US* __restrict__ XBhi, const US* __restrict__ XBlo,
                     float* __restrict__ sjt_b) {
    const int id = blockIdx.x;  // 64 = 4b x 4mt x 4nq
    const int b = id >> 4;
    const int mt = (id >> 2) & 3;
    const int nq = id & 3;
    const int t = threadIdx.x;
    const int lane = t & 63;
    const int w = t >> 6;
    const int arow = lane & 15;
    const int kgrp = lane >> 4;
    const int m0 = mt * 64 + w * 16;
    const size_t abase = (size_t)(b * 256 + m0 + arow) * 256 + kgrp * 8;
    const f32x4 vzero = {0.f, 0.f, 0.f, 0.f};
    f32x4 acc[4];
    #pragma unroll
    for (int cj = 0; cj < 4; ++cj) acc[cj] = vzero;
    #pragma unroll
    for (int kk = 0; kk < 8; ++kk) {
        short8 ahi = *(const short8*)(x1b + abase + kk * 32);
        short8 alo = *(const short8*)(x1lo + abase + kk * 32);
        #pragma unroll
        for (int cj = 0; cj < 4; ++cj) {
            const int nt = nq * 4 + cj;
            const size_t bbase = (size_t)(b * 256 + nt * 16 + arow) * 256 + kk * 32 + kgrp * 8;
            short8 bhi = *(const short8*)(XBhi + bbase);
            short8 blo = *(const short8*)(XBlo + bbase);
            acc[cj] = __builtin_amdgcn_mfma_f32_16x16x32_bf16(ahi, bhi, acc[cj], 0, 0, 0);
            acc[cj] = __builtin_amdgcn_mfma_f32_16x16x32_bf16(ahi, blo, acc[cj], 0, 0, 0);
            acc[cj] = __builtin_amdgcn_mfma_f32_16x16x32_bf16(alo, bhi, acc[cj], 0, 0, 0);
        }
    }
    float* outb = sjt_b + (size_t)b * 65536;
    #pragma unroll
    for (int cj = 0; cj < 4; ++cj) {
        const int nt = nq * 4 + cj;
        #pragma unroll
        for (int r = 0; r < 4; ++r)
            outb[(size_t)(m0 + kgrp * 4 + r) * 256 + nt * 16 + arow] = acc[cj][r];
    }
}

// ---------- kernel 5: fused concat+minus scores + 5x softmax + weighted sums + max ----------
__global__ void final_kernel(const float* __restrict__ S1T, const float* __restrict__ SXT,
                             const float* __restrict__ S2, const float* __restrict__ SY,
                             const float* __restrict__ vc, const float* __restrict__ vm,
                             const float* __restrict__ sjt_b, const float* __restrict__ sjt_s,
                             const float* __restrict__ sjt_d,
                             const US* __restrict__ x0b, const US* __restrict__ x1b,
                             const float* __restrict__ x1, float* __restrict__ outp) {
    __shared__ float srow[5][256];
    __shared__ float s2c[128], syc[128], vc2[128], vm2[128];
    __shared__ float vsums[2];
    const int id = blockIdx.x;
    const int b = id >> 8, m = id & 255;
    const int t = threadIdx.x;
    const size_t bm = (size_t)(b * 256 + m) * 256;

    if (t < 128) {
        s2c[t] = S2[(size_t)(b * 256 + m) * 128 + t] * C2;
        vc2[t] = -2.0f * vc[t];
    } else {
        const int h = t - 128;
        syc[h] = SY[(size_t)(b * 256 + m) * 128 + h] * C2;
        vm2[h] = -2.0f * vm[h];
    }
    if (t < 64) {
        float sv = vc[t] + vc[t + 64];
        #pragma unroll
        for (int off = 32; off >= 1; off >>= 1) sv += __shfl_xor(sv, off);
        if (t == 0) vsums[0] = sv;
    } else if (t < 128) {
        const int l = t - 64;
        float sv = vm[l] + vm[l + 64];
        #pragma unroll
        for (int off = 32; off >= 1; off >>= 1) sv += __shfl_xor(sv, off);
        if (l == 0) vsums[1] = sv;
    }
    __syncthreads();

    // phase A: concat + minus score for column n=t of row m
    {
        const float* s1p = S1T + (size_t)b * 32768 + t;
        const float* sxp = SXT + (size_t)b * 32768 + t;
        float accC = 0.f, accM = 0.f;
        #pragma unroll 4
        for (int h = 0; h < 128; ++h) {
            float s1 = s1p[h * 256];
            float sx = sxp[h * 256];
            float aC = fmaf(s1, C2, s2c[h]);
            float aM = fmaf(sx, C2, -syc[h]);
            accC = fmaf(vc2[h], RCP(EXP2(aC) + 1.0f), accC);
            accM = fmaf(vm2[h], RCP(EXP2(aM) + 1.0f), accM);
        }
        srow[0][t] = accC + vsums[0];
        srow[1][t] = accM + vsums[1];
        srow[2][t] = sjt_b[bm + t];
        srow[3][t] = sjt_s[bm + t];
        srow[4][t] = sjt_d[bm + t];
    }
    __syncthreads();

    const int wv = t >> 6, lane = t & 63;
    for (int r = wv; r < 5; r += 4) {
        float v0 = srow[r][lane], v1 = srow[r][lane + 64];
        float v2 = srow[r][lane + 128], v3 = srow[r][lane + 192];
        float mx = fmaxf(fmaxf(v0, v1), fmaxf(v2, v3));
        #pragma unroll
        for (int off = 32; off >= 1; off >>= 1) mx = fmaxf(mx, __shfl_xor(mx, off));
        v0 = __expf(v0 - mx); v1 = __expf(v1 - mx);
        v2 = __expf(v2 - mx); v3 = __expf(v3 - mx);
        float s = v0 + v1 + v2 + v3;
        #pragma unroll
        for (int off = 32; off >= 1; off >>= 1) s += __shfl_xor(s, off);
        float inv = __fdividef(1.0f, s);
        srow[r][lane] = v0 * inv;       srow[r][lane + 64] = v1 * inv;
        srow[r][lane + 128] = v2 * inv; srow[r][lane + 192] = v3 * inv;
    }
    __syncthreads();

    const US* x0p = x0b + (size_t)b * 65536 + t;
    const US* x1p = x1b + (size_t)b * 65536 + t;
    float aC = 0.f, aM = 0.f, aB = 0.f, aS = 0.f, aD = 0.f;
    #pragma unroll 4
    for (int n = 0; n < 256; ++n) {
        float x0v = bf2f(x0p[n * 256]);
        float x1v = bf2f(x1p[n * 256]);
        aC = fmaf(srow[0][n], x0v, aC);
        aM = fmaf(srow[1][n], x0v, aM);
        aB = fmaf(srow[2][n], x0v, aB);
        aS = fmaf(srow[3][n], x0v, aS);
        aD = fmaf(srow[4][n], x1v, aD);
    }
    float x1orig = x1[bm + t];
    float o = fmaxf(fmaxf(fmaxf(x1orig, aS), fmaxf(aC, aD)), fmaxf(aB, aM));
    outp[bm + t] = o;
}

// ---------- host ----------
extern "C" void kernel_launch(void* const* d_in, const int* in_sizes, int n_in,
                              void* d_out, int out_size, void* d_ws, size_t ws_size,
                              hipStream_t stream) {
    (void)in_sizes; (void)n_in; (void)out_size; (void)ws_size;
    const float* x0  = (const float*)d_in[0];
    const float* x1  = (const float*)d_in[1];
    const float* Wc1 = (const float*)d_in[2];
    const float* Wc2 = (const float*)d_in[3];
    const float* vc  = (const float*)d_in[4];
    const float* Wb  = (const float*)d_in[5];
    const float* Wd1 = (const float*)d_in[6];
    const float* vd1 = (const float*)d_in[7];
    const float* Wd2 = (const float*)d_in[8];
    const float* vd2 = (const float*)d_in[9];
    const float* Wm  = (const float*)d_in[10];
    const float* vm  = (const float*)d_in[11];

    char* ws = (char*)d_ws;
    US*    x0b   = (US*)(ws + 0);          // 524288
    US*    x1b   = (US*)(ws + 524288);
    US*    x0lo  = (US*)(ws + 1048576);
    US*    x1lo  = (US*)(ws + 1572864);
    US*    WcT1  = (US*)(ws + 2097152);    // 65536 each
    US*    WcT2  = (US*)(ws + 2162688);
    US*    WmT   = (US*)(ws + 2228224);
    US*    WdT1  = (US*)(ws + 2293760);
    US*    WdT2  = (US*)(ws + 2359296);
    US*    WbThi = (US*)(ws + 2424832);    // 131072 each
    US*    WbTlo = (US*)(ws + 2555904);
    float* S1T   = (float*)(ws + 2686976); // 524288 each
    float* SXT   = (float*)(ws + 3211264);
    float* S2    = (float*)(ws + 3735552);
    float* SY    = (float*)(ws + 4259840);
    US*    XBhi  = (US*)(ws + 4784128);    // 524288 each
    US*    XBlo  = (US*)(ws + 5308416);
    float* sjt_b = (float*)(ws + 5832704); // 1048576 each
    float* sjt_s = (float*)(ws + 6881280);
    float* sjt_d = (float*)(ws + 7929856); // ends 8978432

    prep_kernel<<<1408, 256, 0, stream>>>(x0, x1, Wc1, Wc2, Wm, Wd1, Wd2, Wb,
                                          x0b, x1b, x0lo, x1lo,
                                          WcT1, WcT2, WmT, WdT1, WdT2, WbThi, WbTlo);
    fused_gemms_kernel<<<192, 256, 0, stream>>>(x0b, x0lo, x1b, WcT1, WcT2, WmT, WbThi, WbTlo,
                                                S1T, SXT, S2, SY, XBhi, XBlo);
    dot_scores_kernel<<<2048, 256, 0, stream>>>(x0b, x1b, x0, x1, WdT1, WdT2, vd1, vd2, sjt_s, sjt_d);
    bilinear_kernel<<<64, 256, 0, stream>>>(x1b, x1lo, XBhi, XBlo, sjt_b);
    final_kernel<<<1024, 256, 0, stream>>>(S1T, SXT, S2, SY, vc, vm, sjt_b, sjt_s, sjt_d,
                                           x0b, x1b, x1, (float*)d_out);
}

// Round 4
// 127.465 us; speedup vs baseline: 2.0141x; 1.5182x over previous
//
#include <hip/hip_runtime.h>
#include <math.h>

typedef short short8 __attribute__((ext_vector_type(8)));
typedef float f32x4 __attribute__((ext_vector_type(4)));
typedef unsigned short US;

#if __has_builtin(__builtin_amdgcn_exp2f)
#define EXP2(x) __builtin_amdgcn_exp2f(x)
#else
#define EXP2(x) exp2f(x)
#endif
#define RCP(x) __builtin_amdgcn_rcpf(x)

#define C2 2.8853900817779268f  /* 2*log2(e) */

// ---------- helpers ----------
__device__ __forceinline__ float bf2f(US u) {
    return __uint_as_float(((unsigned int)u) << 16);
}
// exact RNE float->bf16
__device__ __forceinline__ US f2bf(float f) {
    unsigned int x = __float_as_uint(f);
    return (US)((x + 0x7FFFu + ((x >> 16) & 1u)) >> 16);
}
// round-half-up float->bf16 (cheap, <=0.5ulp)
__device__ __forceinline__ US f2bf_fast(float f) {
    return (US)((__float_as_uint(f) + 0x8000u) >> 16);
}

// B=4, N=M=256, D=256, H=128 (hard-coded)

// ---------- kernel 1: prep (casts + transposes) ----------
__global__ void prep_kernel(const float* __restrict__ x0, const float* __restrict__ x1,
                            const float* __restrict__ Wc1, const float* __restrict__ Wc2,
                            const float* __restrict__ Wm, const float* __restrict__ Wd1,
                            const float* __restrict__ Wd2, const float* __restrict__ Wb,
                            US* __restrict__ x0b, US* __restrict__ x1b,
                            US* __restrict__ x0lo, US* __restrict__ x1lo,
                            US* __restrict__ WcT1, US* __restrict__ WcT2,
                            US* __restrict__ WmT, US* __restrict__ WdT1, US* __restrict__ WdT2,
                            US* __restrict__ WbThi, US* __restrict__ WbTlo) {
    const int id = blockIdx.x;
    const int t = threadIdx.x;
    if (id < 512) {
        const int tensor = id >> 8;
        const float* src = tensor ? x1 : x0;
        US* dhi = tensor ? x1b : x0b;
        US* dlo = tensor ? x1lo : x0lo;
        const int idx = (id & 255) * 256 + t;  // float4 index
        float4 v = ((const float4*)src)[idx];
        float f[4] = {v.x, v.y, v.z, v.w};
        ushort4 hi, lo;
        US* hp = (US*)&hi;
        US* lp = (US*)&lo;
        #pragma unroll
        for (int j = 0; j < 4; ++j) {
            US h = f2bf(f[j]);
            hp[j] = h;
            lp[j] = f2bf(f[j] - bf2f(h));
        }
        ((ushort4*)dhi)[idx] = hi;
        ((ushort4*)dlo)[idx] = lo;
    } else if (id < 1152) {
        const int j = id - 512;
        const int mat = j >> 7;
        const float* src = (mat == 0) ? Wc1 : (mat == 1) ? Wc2 : (mat == 2) ? Wm : (mat == 3) ? Wd1 : Wd2;
        US* dst = (mat == 0) ? WcT1 : (mat == 1) ? WcT2 : (mat == 2) ? WmT : (mat == 3) ? WdT1 : WdT2;
        const int el = (j & 127) * 256 + t;
        const int d = el >> 7, h = el & 127;
        dst[h * 256 + d] = f2bf(src[d * 128 + h]);
    } else {
        const int j = id - 1152;
        const int el = j * 256 + t;
        const int d = el >> 8, dp = el & 255;
        float v = Wb[d * 256 + dp];
        US h = f2bf(v);
        WbThi[dp * 256 + d] = h;
        WbTlo[dp * 256 + d] = f2bf(v - bf2f(h));
    }
}

// ---------- kernel 2: combo — blocks 0..191: small GEMMs; blocks 192..2239: dot-att scores ----------
__global__ __launch_bounds__(256, 2)
void combo_kernel(const US* __restrict__ x0b, const US* __restrict__ x0lo,
                  const US* __restrict__ x1b,
                  const US* __restrict__ WcT1, const US* __restrict__ WcT2,
                  const US* __restrict__ WmT,
                  const US* __restrict__ WbThi, const US* __restrict__ WbTlo,
                  const US* __restrict__ WdT1, const US* __restrict__ WdT2,
                  const float* __restrict__ x0, const float* __restrict__ x1,
                  const float* __restrict__ vd1, const float* __restrict__ vd2,
                  float* __restrict__ S1T, float* __restrict__ SXT,
                  float* __restrict__ S2, float* __restrict__ SY,
                  unsigned* __restrict__ XBpT,
                  float* __restrict__ sjt_s, float* __restrict__ sjt_d) {
    __shared__ __align__(16) US Wp[128 * 256];  // 64 KB, 16B-block XOR swizzled (dot branch)
    const int bid = blockIdx.x;
    const int t = threadIdx.x;
    const int lane = t & 63;
    const int w = t >> 6;
    const int arow = lane & 15;
    const int kgrp = lane >> 4;

    if (bid < 192) {
        // ================= small-GEMM branch =================
        const int id = bid;                   // 192 = 4b x 3which x 16rg
        const int rg = id & 15;
        const int t2 = id >> 4;               // 0..11
        const int b = t2 / 3;
        const int which = t2 - b * 3;

        const US* A = (which == 2 ? x1b : x0b) + (size_t)(b * 256 + rg * 16 + arow) * 256 + kgrp * 8;
        const US* Alo = x0lo + (size_t)(b * 256 + rg * 16 + arow) * 256 + kgrp * 8;

        const f32x4 vzero = {0.f, 0.f, 0.f, 0.f};
        f32x4 acc[4];
        #pragma unroll
        for (int cj = 0; cj < 4; ++cj) acc[cj] = vzero;

        if (which == 1) {
            #pragma unroll
            for (int kk = 0; kk < 8; ++kk) {
                short8 ahi = *(const short8*)(A + kk * 32);
                short8 alo = *(const short8*)(Alo + kk * 32);
                #pragma unroll
                for (int cj = 0; cj < 4; ++cj) {
                    const int ct = w * 4 + cj;
                    short8 bhi = *(const short8*)(WbThi + (ct * 16 + arow) * 256 + kk * 32 + kgrp * 8);
                    short8 blo = *(const short8*)(WbTlo + (ct * 16 + arow) * 256 + kk * 32 + kgrp * 8);
                    acc[cj] = __builtin_amdgcn_mfma_f32_16x16x32_bf16(ahi, bhi, acc[cj], 0, 0, 0);
                    acc[cj] = __builtin_amdgcn_mfma_f32_16x16x32_bf16(ahi, blo, acc[cj], 0, 0, 0);
                    acc[cj] = __builtin_amdgcn_mfma_f32_16x16x32_bf16(alo, bhi, acc[cj], 0, 0, 0);
                }
            }
            #pragma unroll
            for (int cj = 0; cj < 4; ++cj) {
                const int ct = w * 4 + cj;
                #pragma unroll
                for (int r = 0; r < 4; ++r) {
                    const int n = rg * 16 + kgrp * 4 + r;
                    const int dp = ct * 16 + arow;
                    float val = acc[cj][r];
                    US h = f2bf(val);
                    US l = f2bf(val - bf2f(h));
                    XBpT[(size_t)(b * 256 + dp) * 256 + n] = ((unsigned)h << 16) | (unsigned)l;
                }
            }
        } else {
            const US* WA = (which == 0) ? WcT1 : WcT2;
            #pragma unroll
            for (int kk = 0; kk < 8; ++kk) {
                short8 a = *(const short8*)(A + kk * 32);
                #pragma unroll
                for (int cj = 0; cj < 4; ++cj) {
                    const int ct = w * 4 + cj;
                    const US* brow = (ct < 8) ? (WA + (ct * 16 + arow) * 256)
                                              : (WmT + ((ct - 8) * 16 + arow) * 256);
                    short8 bf = *(const short8*)(brow + kk * 32 + kgrp * 8);
                    acc[cj] = __builtin_amdgcn_mfma_f32_16x16x32_bf16(a, bf, acc[cj], 0, 0, 0);
                }
            }
            #pragma unroll
            for (int cj = 0; cj < 4; ++cj) {
                const int ct = w * 4 + cj;
                #pragma unroll
                for (int r = 0; r < 4; ++r) {
                    const int row = rg * 16 + kgrp * 4 + r;
                    const int h = (ct < 8) ? ct * 16 + arow : (ct - 8) * 16 + arow;
                    float val = acc[cj][r];
                    if (which == 0) {
                        float* dst = (ct < 8) ? S1T : SXT;
                        dst[(size_t)(b * 128 + h) * 256 + row] = val;
                    } else {
                        float* dst = (ct < 8) ? S2 : SY;
                        dst[(size_t)(b * 256 + row) * 128 + h] = val;
                    }
                }
            }
        }
        return;
    }

    // ================= dot-scores branch =================
    const int id2 = bid - 192;
    const int mech = id2 >> 10;
    const int rem = id2 & 1023;
    const int b = rem >> 8;
    const int m = rem & 255;
    const US* xA = (mech == 0 ? x0b : x1b) + (size_t)b * 65536;
    const float* yrow = (mech == 0 ? x1 : x0) + (size_t)(b * 256 + m) * 256;
    const US* WT = (mech == 0 ? WdT1 : WdT2);
    const float* v = (mech == 0 ? vd1 : vd2);
    float* out = (mech == 0 ? sjt_s : sjt_d) + (size_t)(b * 256 + m) * 256;

    // ---- stage full W'[h][d] = y[d]*WdT[h][d], one pass ----
    {
        const int db = t & 31;     // d-block (8 d's)
        const int hset = t >> 5;   // 0..7 -> 16 h-rows each
        float yv[8];
        {
            float4 y0 = *(const float4*)(yrow + db * 8);
            float4 y1 = *(const float4*)(yrow + db * 8 + 4);
            yv[0] = y0.x; yv[1] = y0.y; yv[2] = y0.z; yv[3] = y0.w;
            yv[4] = y1.x; yv[5] = y1.y; yv[6] = y1.z; yv[7] = y1.w;
        }
        #pragma unroll
        for (int k = 0; k < 16; ++k) {
            const int hq = hset * 16 + k;
            short8 wv = *(const short8*)(WT + (size_t)hq * 256 + db * 8);
            short8 ov;
            #pragma unroll
            for (int j = 0; j < 8; ++j)
                ov[j] = (short)f2bf_fast(bf2f((US)wv[j]) * yv[j]);
            *(short8*)(&Wp[hq * 256 + ((db ^ (hq & 7)) << 3)]) = ov;
        }
    }
    __syncthreads();

    // v-vector per lane: h-tile j -> h = j*16 + arow
    float v2[8], vsum = 0.f;
    #pragma unroll
    for (int j = 0; j < 8; ++j) {
        float vvv = v[j * 16 + arow];
        v2[j] = -2.0f * vvv;
        vsum += vvv;
    }

    const f32x4 vzero = {0.f, 0.f, 0.f, 0.f};
    for (int p = 0; p < 2; ++p) {  // n-half passes
        f32x4 acc[2][8];
        #pragma unroll
        for (int i = 0; i < 2; ++i)
            #pragma unroll
            for (int j = 0; j < 8; ++j) acc[i][j] = vzero;

        #pragma unroll
        for (int kk = 0; kk < 8; ++kk) {
            const int nbase = p * 128 + w * 32 + arow;
            short8 af0 = *(const short8*)(xA + (size_t)nbase * 256 + kk * 32 + kgrp * 8);
            short8 af1 = *(const short8*)(xA + (size_t)(nbase + 16) * 256 + kk * 32 + kgrp * 8);
            const int sb = (kk * 4 + kgrp) ^ (arow & 7);
            #pragma unroll
            for (int j = 0; j < 8; ++j) {
                short8 bfr = *(const short8*)(&Wp[(j * 16 + arow) * 256 + sb * 8]);
                acc[0][j] = __builtin_amdgcn_mfma_f32_16x16x32_bf16(af0, bfr, acc[0][j], 0, 0, 0);
                acc[1][j] = __builtin_amdgcn_mfma_f32_16x16x32_bf16(af1, bfr, acc[1][j], 0, 0, 0);
            }
        }
        // fold v*tanh(s) = v + v2*rcp(exp2(s*C2)+1), reduce over 16 h-lanes, write
        #pragma unroll
        for (int i = 0; i < 2; ++i)
            #pragma unroll
            for (int r = 0; r < 4; ++r) {
                float pp = vsum;
                #pragma unroll
                for (int j = 0; j < 8; ++j)
                    pp = fmaf(v2[j], RCP(EXP2(acc[i][j][r] * C2) + 1.0f), pp);
                pp += __shfl_xor(pp, 1);
                pp += __shfl_xor(pp, 2);
                pp += __shfl_xor(pp, 4);
                pp += __shfl_xor(pp, 8);
                if (arow == 0) out[p * 128 + w * 32 + i * 16 + kgrp * 4 + r] = pp;
            }
    }
}

// ---------- kernel 3: fused concat+minus scores + bilinear matvec + 5x softmax + sums + max ----------
__global__ void final_kernel(const float* __restrict__ S1T, const float* __restrict__ SXT,
                             const float* __restrict__ S2, const float* __restrict__ SY,
                             const float* __restrict__ vc, const float* __restrict__ vm,
                             const unsigned* __restrict__ XBpT,
                             const float* __restrict__ sjt_s, const float* __restrict__ sjt_d,
                             const US* __restrict__ x0b, const US* __restrict__ x1b,
                             const float* __restrict__ x1, float* __restrict__ outp) {
    __shared__ float srow[5][256];
    __shared__ float s2c[128], syc[128], vc2[128], vm2[128];
    __shared__ float ylds[256];
    __shared__ float vsums[2];
    const int id = blockIdx.x;
    const int b = id >> 8, m = id & 255;
    const int t = threadIdx.x;
    const size_t bm = (size_t)(b * 256 + m) * 256;

    ylds[t] = x1[bm + t];
    if (t < 128) {
        s2c[t] = S2[(size_t)(b * 256 + m) * 128 + t] * C2;
        vc2[t] = -2.0f * vc[t];
    } else {
        const int h = t - 128;
        syc[h] = SY[(size_t)(b * 256 + m) * 128 + h] * C2;
        vm2[h] = -2.0f * vm[h];
    }
    if (t < 64) {
        float sv = vc[t] + vc[t + 64];
        #pragma unroll
        for (int off = 32; off >= 1; off >>= 1) sv += __shfl_xor(sv, off);
        if (t == 0) vsums[0] = sv;
    } else if (t < 128) {
        const int l = t - 64;
        float sv = vm[l] + vm[l + 64];
        #pragma unroll
        for (int off = 32; off >= 1; off >>= 1) sv += __shfl_xor(sv, off);
        if (l == 0) vsums[1] = sv;
    }
    __syncthreads();

    // phase A: concat + minus scores for column n=t of row m
    {
        const float* s1p = S1T + (size_t)b * 32768 + t;
        const float* sxp = SXT + (size_t)b * 32768 + t;
        float accC = 0.f, accM = 0.f;
        #pragma unroll 4
        for (int h = 0; h < 128; ++h) {
            float s1 = s1p[h * 256];
            float sx = sxp[h * 256];
            float aC = fmaf(s1, C2, s2c[h]);
            float aM = fmaf(sx, C2, -syc[h]);
            accC = fmaf(vc2[h], RCP(EXP2(aC) + 1.0f), accC);
            accM = fmaf(vm2[h], RCP(EXP2(aM) + 1.0f), accM);
        }
        srow[0][t] = accC + vsums[0];
        srow[1][t] = accM + vsums[1];
    }
    // phase B: bilinear score sjt_b[m][n=t] = sum_dp XB[n,dp]*y[dp]  (hi/lo packed, fp32 accum)
    {
        const unsigned* xbp = XBpT + (size_t)b * 65536 + t;
        float aB = 0.f;
        #pragma unroll 4
        for (int dp = 0; dp < 256; ++dp) {
            unsigned u = xbp[dp * 256];
            float yv = ylds[dp];
            aB = fmaf(__uint_as_float(u & 0xFFFF0000u), yv, aB);
            aB = fmaf(__uint_as_float(u << 16), yv, aB);
        }
        srow[2][t] = aB;
    }
    srow[3][t] = sjt_s[bm + t];
    srow[4][t] = sjt_d[bm + t];
    __syncthreads();

    const int wv = t >> 6, lane = t & 63;
    for (int r = wv; r < 5; r += 4) {
        float v0 = srow[r][lane], v1 = srow[r][lane + 64];
        float v2 = srow[r][lane + 128], v3 = srow[r][lane + 192];
        float mx = fmaxf(fmaxf(v0, v1), fmaxf(v2, v3));
        #pragma unroll
        for (int off = 32; off >= 1; off >>= 1) mx = fmaxf(mx, __shfl_xor(mx, off));
        v0 = __expf(v0 - mx); v1 = __expf(v1 - mx);
        v2 = __expf(v2 - mx); v3 = __expf(v3 - mx);
        float s = v0 + v1 + v2 + v3;
        #pragma unroll
        for (int off = 32; off >= 1; off >>= 1) s += __shfl_xor(s, off);
        float inv = __fdividef(1.0f, s);
        srow[r][lane] = v0 * inv;       srow[r][lane + 64] = v1 * inv;
        srow[r][lane + 128] = v2 * inv; srow[r][lane + 192] = v3 * inv;
    }
    __syncthreads();

    const US* x0p = x0b + (size_t)b * 65536 + t;
    const US* x1p = x1b + (size_t)b * 65536 + t;
    float aC = 0.f, aM = 0.f, aB = 0.f, aS = 0.f, aD = 0.f;
    #pragma unroll 4
    for (int n = 0; n < 256; ++n) {
        float x0v = bf2f(x0p[n * 256]);
        float x1v = bf2f(x1p[n * 256]);
        aC = fmaf(srow[0][n], x0v, aC);
        aM = fmaf(srow[1][n], x0v, aM);
        aB = fmaf(srow[2][n], x0v, aB);
        aS = fmaf(srow[3][n], x0v, aS);
        aD = fmaf(srow[4][n], x1v, aD);
    }
    float x1orig = x1[bm + t];
    float o = fmaxf(fmaxf(fmaxf(x1orig, aS), fmaxf(aC, aD)), fmaxf(aB, aM));
    outp[bm + t] = o;
}

// ---------- host ----------
extern "C" void kernel_launch(void* const* d_in, const int* in_sizes, int n_in,
                              void* d_out, int out_size, void* d_ws, size_t ws_size,
                              hipStream_t stream) {
    (void)in_sizes; (void)n_in; (void)out_size; (void)ws_size;
    const float* x0  = (const float*)d_in[0];
    const float* x1  = (const float*)d_in[1];
    const float* Wc1 = (const float*)d_in[2];
    const float* Wc2 = (const float*)d_in[3];
    const float* vc  = (const float*)d_in[4];
    const float* Wb  = (const float*)d_in[5];
    const float* Wd1 = (const float*)d_in[6];
    const float* vd1 = (const float*)d_in[7];
    const float* Wd2 = (const float*)d_in[8];
    const float* vd2 = (const float*)d_in[9];
    const float* Wm  = (const float*)d_in[10];
    const float* vm  = (const float*)d_in[11];

    char* ws = (char*)d_ws;
    US*       x0b   = (US*)(ws + 0);          // 524288
    US*       x1b   = (US*)(ws + 524288);
    US*       x0lo  = (US*)(ws + 1048576);
    US*       x1lo  = (US*)(ws + 1572864);
    US*       WcT1  = (US*)(ws + 2097152);    // 65536 each
    US*       WcT2  = (US*)(ws + 2162688);
    US*       WmT   = (US*)(ws + 2228224);
    US*       WdT1  = (US*)(ws + 2293760);
    US*       WdT2  = (US*)(ws + 2359296);
    US*       WbThi = (US*)(ws + 2424832);    // 131072 each
    US*       WbTlo = (US*)(ws + 2555904);
    float*    S1T   = (float*)(ws + 2686976); // 524288 each
    float*    SXT   = (float*)(ws + 3211264);
    float*    S2    = (float*)(ws + 3735552);
    float*    SY    = (float*)(ws + 4259840);
    unsigned* XBpT  = (unsigned*)(ws + 4784128); // 1048576
    float*    sjt_s = (float*)(ws + 5832704);    // 1048576
    float*    sjt_d = (float*)(ws + 6881280);    // ends 7929856

    prep_kernel<<<1408, 256, 0, stream>>>(x0, x1, Wc1, Wc2, Wm, Wd1, Wd2, Wb,
                                          x0b, x1b, x0lo, x1lo,
                                          WcT1, WcT2, WmT, WdT1, WdT2, WbThi, WbTlo);
    combo_kernel<<<2240, 256, 0, stream>>>(x0b, x0lo, x1b, WcT1, WcT2, WmT, WbThi, WbTlo,
                                           WdT1, WdT2, x0, x1, vd1, vd2,
                                           S1T, SXT, S2, SY, XBpT, sjt_s, sjt_d);
    final_kernel<<<1024, 256, 0, stream>>>(S1T, SXT, S2, SY, vc, vm, XBpT, sjt_s, sjt_d,
                                           x0b, x1b, x1, (float*)d_out);
}